// Round 8
// baseline (102.329 us; speedup 1.0000x reference)
//
#include <hip/hip_runtime.h>
#include <stdint.h>

// ---------------------------------------------------------------------------
// Problem constants (from reference)
// ---------------------------------------------------------------------------
#define EMB   256
#define HEADS 8
#define KMIX  8
#define GADD  2
#define RADD  2
#define REGION 64
#define STRIDE 32
#define BB    4
#define TT    4096
#define TP    128
#define VS    48
#define HID   1024
#define NQ    2048

#define RNG_PARTITIONABLE 1

// ---------------------------------------------------------------------------
// Threefry-2x32 (JAX exact)
// ---------------------------------------------------------------------------
__device__ __forceinline__ uint32_t rotl32(uint32_t x, int d) {
  return (x << d) | (x >> (32 - d));
}
__device__ __forceinline__ void tf2x32(uint32_t k0, uint32_t k1,
                                       uint32_t x0, uint32_t x1,
                                       uint32_t& o0, uint32_t& o1) {
  uint32_t ks2 = k0 ^ k1 ^ 0x1BD11BDAu;
  x0 += k0; x1 += k1;
#define TFR(r) { x0 += x1; x1 = rotl32(x1, r); x1 ^= x0; }
  TFR(13) TFR(15) TFR(26) TFR(6)
  x0 += k1; x1 += ks2 + 1u;
  TFR(17) TFR(29) TFR(16) TFR(24)
  x0 += ks2; x1 += k0 + 2u;
  TFR(13) TFR(15) TFR(26) TFR(6)
  x0 += k0; x1 += k1 + 3u;
  TFR(17) TFR(29) TFR(16) TFR(24)
  x0 += k1; x1 += ks2 + 4u;
  TFR(13) TFR(15) TFR(26) TFR(6)
  x0 += ks2; x1 += k0 + 5u;
#undef TFR
  o0 = x0; o1 = x1;
}

// ---------------------------------------------------------------------------
// Fused init: blocks [0,512) extract sel rows; blocks [512,544) do RNG.
// ---------------------------------------------------------------------------
__global__ __launch_bounds__(256) void init_kernel(
    const float* __restrict__ x, float* __restrict__ xsel,
    int* __restrict__ grand, int* __restrict__ rrand)
{
  const int blk = blockIdx.x, tid = threadIdx.x;
  if (blk < BB * TP) {
    const int b = blk >> 7, p = blk & 127;
    const int selp = STRIDE * p + STRIDE - 1;
    xsel[(size_t)blk * EMB + tid] = x[((size_t)b * TT + selp) * EMB + tid];
    return;
  }
  int i = (blk - BB * TP) * 256 + tid;
#if RNG_PARTITIONABLE
  uint32_t kg0, kg1, kr0, kr1;
  tf2x32(0u, 42u, 0u, 0u, kg0, kg1);
  tf2x32(0u, 42u, 0u, 1u, kr0, kr1);
  uint32_t g2k0, g2k1, r2k0, r2k1;
  tf2x32(kg0, kg1, 0u, 1u, g2k0, g2k1);
  tf2x32(kr0, kr1, 0u, 1u, r2k0, r2k1);
  if (i < BB * TP * KMIX * GADD) {
    uint32_t o0, o1;
    tf2x32(g2k0, g2k1, 0u, (uint32_t)i, o0, o1);
    grand[i] = (int)((o0 ^ o1) & 4095u);
    tf2x32(r2k0, r2k1, 0u, (uint32_t)i, o0, o1);
    rrand[i] = (int)((o0 ^ o1) & 63u);
  }
#else
  uint32_t a0, a1, b0, b1;
  tf2x32(0u, 42u, 0u, 2u, a0, a1);
  tf2x32(0u, 42u, 1u, 3u, b0, b1);
  uint32_t kg0 = a0, kg1 = b0, kr0 = a1, kr1 = b1;
  uint32_t c0, c1, d0, d1;
  tf2x32(kg0, kg1, 0u, 2u, c0, c1);
  tf2x32(kg0, kg1, 1u, 3u, d0, d1);
  uint32_t g2k0 = c1, g2k1 = d1;
  tf2x32(kr0, kr1, 0u, 2u, c0, c1);
  tf2x32(kr0, kr1, 1u, 3u, d0, d1);
  uint32_t r2k0 = c1, r2k1 = d1;
  if (i < 4096) {
    uint32_t o0, o1;
    tf2x32(g2k0, g2k1, (uint32_t)i, (uint32_t)(i + 4096), o0, o1);
    grand[i]        = (int)(o0 & 4095u);
    grand[i + 4096] = (int)(o1 & 4095u);
    tf2x32(r2k0, r2k1, (uint32_t)i, (uint32_t)(i + 4096), o0, o1);
    rrand[i]        = (int)(o0 & 63u);
    rrand[i + 4096] = (int)(o1 & 63u);
  }
#endif
}

// ---------------------------------------------------------------------------
// Fused weight precompute. z in [0,8): M_h = (Wq_h @ Wk_h^T)/16 (NT).
// z in [8,16): PV_h = Wv_h @ Wu_h (NN). Tile M=32, N=64, BK=32.
// ---------------------------------------------------------------------------
__global__ __launch_bounds__(256) void wpre_kernel(
    const float* __restrict__ Wq, const float* __restrict__ Wk,
    const float* __restrict__ Wv, const float* __restrict__ Wu,
    float* __restrict__ M8, float* __restrict__ PV)
{
  const int tid = threadIdx.x;
  const int tx = tid & 15, ty = tid >> 4;
  const int n0 = blockIdx.x * 64, m0 = blockIdx.y * 32;
  const int zz = blockIdx.z;

  float acc[2][4];
#pragma unroll
  for (int i = 0; i < 2; i++)
#pragma unroll
    for (int j = 0; j < 4; j++) acc[i][j] = 0.0f;

  if (zz < HEADS) {
    // NT path: A = Wq_h [256 x 256] lda NQ, B = Wk_h, C = M8_h
    const float* A = Wq + zz * 256;
    const float* B = Wk + zz * 256;
    float* C = M8 + (size_t)zz * EMB * EMB;
    __shared__ float As[32][33];
    __shared__ float Bs[64][33];
    for (int k0 = 0; k0 < EMB; k0 += 32) {
      {
        int r = tid >> 3, kq = tid & 7;
        float4 v = *(const float4*)(A + (size_t)(m0 + r) * NQ + k0 + kq * 4);
        As[r][kq * 4 + 0] = v.x; As[r][kq * 4 + 1] = v.y;
        As[r][kq * 4 + 2] = v.z; As[r][kq * 4 + 3] = v.w;
      }
#pragma unroll
      for (int rr = 0; rr < 2; rr++) {
        int c = tid * 2 + rr;
        int r = c >> 3, kq = c & 7;
        float4 v = *(const float4*)(B + (size_t)(n0 + r) * NQ + k0 + kq * 4);
        Bs[r][kq * 4 + 0] = v.x; Bs[r][kq * 4 + 1] = v.y;
        Bs[r][kq * 4 + 2] = v.z; Bs[r][kq * 4 + 3] = v.w;
      }
      __syncthreads();
#pragma unroll
      for (int kk = 0; kk < 32; kk++) {
        float a0 = As[ty * 2 + 0][kk], a1 = As[ty * 2 + 1][kk];
        float b0 = Bs[tx * 4 + 0][kk], b1 = Bs[tx * 4 + 1][kk];
        float b2 = Bs[tx * 4 + 2][kk], b3 = Bs[tx * 4 + 3][kk];
        acc[0][0] = fmaf(a0, b0, acc[0][0]); acc[0][1] = fmaf(a0, b1, acc[0][1]);
        acc[0][2] = fmaf(a0, b2, acc[0][2]); acc[0][3] = fmaf(a0, b3, acc[0][3]);
        acc[1][0] = fmaf(a1, b0, acc[1][0]); acc[1][1] = fmaf(a1, b1, acc[1][1]);
        acc[1][2] = fmaf(a1, b2, acc[1][2]); acc[1][3] = fmaf(a1, b3, acc[1][3]);
      }
      __syncthreads();
    }
#pragma unroll
    for (int i = 0; i < 2; i++) {
      float* cp = C + (size_t)(m0 + ty * 2 + i) * EMB + n0 + tx * 4;
      *(float4*)cp = make_float4(acc[i][0] * 0.0625f, acc[i][1] * 0.0625f,
                                 acc[i][2] * 0.0625f, acc[i][3] * 0.0625f);
    }
  } else {
    // NN path: A = Wv_h [256 x 256] lda NQ, W = Wu_h [256 x 256] ldw EMB
    const int hh = zz - HEADS;
    const float* A = Wv + hh * 256;
    const float* W = Wu + (size_t)hh * 256 * EMB;
    float* C = PV + (size_t)hh * EMB * EMB;
    __shared__ float As2[32][33];
    __shared__ __align__(16) float Bs2[32][64];
    for (int k0 = 0; k0 < EMB; k0 += 32) {
      {
        int r = tid >> 3, kq = tid & 7;
        float4 v = *(const float4*)(A + (size_t)(m0 + r) * NQ + k0 + kq * 4);
        As2[r][kq * 4 + 0] = v.x; As2[r][kq * 4 + 1] = v.y;
        As2[r][kq * 4 + 2] = v.z; As2[r][kq * 4 + 3] = v.w;
      }
#pragma unroll
      for (int rr = 0; rr < 2; rr++) {
        int c = tid * 2 + rr;
        int kk = c >> 4, n4 = c & 15;
        *(float4*)(&Bs2[kk][n4 * 4]) =
            *(const float4*)(W + (size_t)(k0 + kk) * EMB + n0 + n4 * 4);
      }
      __syncthreads();
#pragma unroll
      for (int kk = 0; kk < 32; kk++) {
        float a0 = As2[ty * 2 + 0][kk], a1 = As2[ty * 2 + 1][kk];
        float4 b4 = *(const float4*)&Bs2[kk][tx * 4];
        acc[0][0] = fmaf(a0, b4.x, acc[0][0]); acc[0][1] = fmaf(a0, b4.y, acc[0][1]);
        acc[0][2] = fmaf(a0, b4.z, acc[0][2]); acc[0][3] = fmaf(a0, b4.w, acc[0][3]);
        acc[1][0] = fmaf(a1, b4.x, acc[1][0]); acc[1][1] = fmaf(a1, b4.y, acc[1][1]);
        acc[1][2] = fmaf(a1, b4.z, acc[1][2]); acc[1][3] = fmaf(a1, b4.w, acc[1][3]);
      }
      __syncthreads();
    }
#pragma unroll
    for (int i = 0; i < 2; i++) {
      float* cp = C + (size_t)(m0 + ty * 2 + i) * EMB + n0 + tx * 4;
      *(float4*)cp = make_float4(acc[i][0], acc[i][1], acc[i][2], acc[i][3]);
    }
  }
}

// ---------------------------------------------------------------------------
// NN GEMM (batched over z): C[m][n] = sum_k A[m][k] * W[k][n]
// Tile M=32, N=64, BK=32; 256 threads; 2x4 per thread.
// ---------------------------------------------------------------------------
__global__ __launch_bounds__(256) void gemm_nn(
    const float* __restrict__ A, int lda, size_t Az,
    const float* __restrict__ W, int ldw, size_t Wz,
    float* __restrict__ C, int ldc, size_t Cz,
    int kLen)
{
  A += (size_t)blockIdx.z * Az;
  W += (size_t)blockIdx.z * Wz;
  C += (size_t)blockIdx.z * Cz;
  const int tid = threadIdx.x;
  const int tx = tid & 15, ty = tid >> 4;
  const int n0 = blockIdx.x * 64, m0 = blockIdx.y * 32;

  __shared__ float As[32][33];
  __shared__ __align__(16) float Bs[32][64];

  float acc[2][4];
#pragma unroll
  for (int i = 0; i < 2; i++)
#pragma unroll
    for (int j = 0; j < 4; j++) acc[i][j] = 0.0f;

  for (int k0 = 0; k0 < kLen; k0 += 32) {
    {
      int r = tid >> 3, kq = tid & 7;
      float4 v = *(const float4*)(A + (size_t)(m0 + r) * lda + k0 + kq * 4);
      As[r][kq * 4 + 0] = v.x; As[r][kq * 4 + 1] = v.y;
      As[r][kq * 4 + 2] = v.z; As[r][kq * 4 + 3] = v.w;
    }
    {
#pragma unroll
      for (int rr = 0; rr < 2; rr++) {
        int c = tid * 2 + rr;
        int kk = c >> 4, n4 = c & 15;
        *(float4*)(&Bs[kk][n4 * 4]) =
            *(const float4*)(W + (size_t)(k0 + kk) * ldw + n0 + n4 * 4);
      }
    }
    __syncthreads();
#pragma unroll
    for (int kk = 0; kk < 32; kk++) {
      float a0 = As[ty * 2 + 0][kk];
      float a1 = As[ty * 2 + 1][kk];
      float4 b4 = *(const float4*)&Bs[kk][tx * 4];
      acc[0][0] = fmaf(a0, b4.x, acc[0][0]);
      acc[0][1] = fmaf(a0, b4.y, acc[0][1]);
      acc[0][2] = fmaf(a0, b4.z, acc[0][2]);
      acc[0][3] = fmaf(a0, b4.w, acc[0][3]);
      acc[1][0] = fmaf(a1, b4.x, acc[1][0]);
      acc[1][1] = fmaf(a1, b4.y, acc[1][1]);
      acc[1][2] = fmaf(a1, b4.z, acc[1][2]);
      acc[1][3] = fmaf(a1, b4.w, acc[1][3]);
    }
    __syncthreads();
  }

#pragma unroll
  for (int i = 0; i < 2; i++) {
    float* cp = C + (size_t)(m0 + ty * 2 + i) * ldc + n0 + tx * 4;
    *(float4*)cp = make_float4(acc[i][0], acc[i][1], acc[i][2], acc[i][3]);
  }
}

// ---------------------------------------------------------------------------
__device__ __forceinline__ float softplus_f(float v) {
  return fmaxf(v, 0.0f) + log1pf(expf(-fabsf(v)));
}

__global__ __launch_bounds__(256) void params2_kernel(
    const float* __restrict__ hid0,
    const float* __restrict__ W1,
    const float* __restrict__ b1,
    const float* __restrict__ W2,
    const float* __restrict__ b2,
    const int* __restrict__ grand, const int* __restrict__ rrand,
    int* __restrict__ idx_out, float* __restrict__ w_out)
{
  const int bp = blockIdx.x;
  const int b = bp >> 7, p = bp & 127;
  const int selp = STRIDE * p + STRIDE - 1;
  const int tid = threadIdx.x;
  const float coordp = (float)p / (float)TP;

  __shared__ float shid[HID];
  __shared__ float spartial[256];
  __shared__ float spar[2 * KMIX];
  __shared__ float sm[KMIX], ss[KMIX];
  __shared__ int   sidx[VS];
  __shared__ float sidxf[VS];
  __shared__ int   svalid[VS];
  __shared__ float sprops[KMIX][VS];
  __shared__ float sden[KMIX];

#pragma unroll
  for (int q = 0; q < HID / 256; q++) {
    int j = q * 256 + tid;
    shid[j] = fmaxf(hid0[(size_t)bp * HID + j] + coordp * W1[(size_t)EMB * HID + j] + b1[j], 0.0f);
  }
  __syncthreads();

  {
    int o = tid & 15, g = tid >> 4;
    float pa = 0.0f;
    for (int jj = 0; jj < 64; jj++) {
      int j = g * 64 + jj;
      pa = fmaf(shid[j], W2[j * (2 * KMIX) + o], pa);
    }
    spartial[o * 16 + g] = pa;
  }
  __syncthreads();
  if (tid < 2 * KMIX) {
    float acc = 0.0f;
    for (int g = 0; g < 16; g++) acc += spartial[tid * 16 + g];
    spar[tid] = acc + b2[tid];
  }
  __syncthreads();

  if (tid < KMIX) {
    float m = (float)selp - 3.0f * softplus_f(spar[tid]);
    m = fminf(fmaxf(m, 0.0f), (float)(TT - 1));
    sm[tid] = m;
    ss[tid] = (softplus_f(spar[KMIX + tid] + 2.0f) + 0.05f) * (float)TT * 0.1f;
  }
  __syncthreads();

  if (tid < VS) {
    int kk = tid / 6, jj = tid % 6;
    float fl = floorf(sm[kk]);
    float v;
    if (jj == 0) v = fl;
    else if (jj == 1) v = fl + 1.0f;
    else if (jj < 4) v = (float)grand[(bp * KMIX + kk) * GADD + (jj - 2)];
    else {
      float lo = fminf(fmaxf(fl - (float)(REGION / 2), 0.0f), (float)(TT - REGION));
      v = lo + (float)rrand[(bp * KMIX + kk) * RADD + (jj - 4)];
    }
    v = fminf(fmaxf(v, 0.0f), (float)(TT - 1));
    int ii = (int)v;
    sidx[tid] = ii;
    sidxf[tid] = (float)ii;
  }
  __syncthreads();

  if (tid < VS) {
    int d = 0;
    for (int u = 0; u < tid; u++) d |= (sidx[u] == sidx[tid]);
    svalid[tid] = (!d) && (sidx[tid] <= selp);
  }
  __syncthreads();

  for (int l = tid; l < KMIX * VS; l += 256) {
    int kk = l / VS, v = l - kk * VS;
    float z = (sidxf[v] - sm[kk]) / ss[kk];
    sprops[kk][v] = svalid[v] ? expf(-0.5f * z * z) : 0.0f;
  }
  __syncthreads();
  if (tid < KMIX) {
    float den = 0.0f;
    for (int v = 0; v < VS; v++) den += sprops[tid][v];
    sden[tid] = den;
  }
  __syncthreads();

  if (tid < VS) {
    float w = 0.0f;
    for (int kk = 0; kk < KMIX; kk++) w += sprops[kk][tid] / sden[kk];
    w_out[(size_t)bp * VS + tid] = w;
    idx_out[(size_t)bp * VS + tid] = sidx[tid];
  }
}

// ---------------------------------------------------------------------------
// Attention, one 512-thread block per bp; wave = head; 1 barrier.
// ---------------------------------------------------------------------------
__global__ __launch_bounds__(512) void attn4_kernel(
    const float* __restrict__ x,     // [B,T,EMB]
    const float* __restrict__ qk,    // [B*TP, NQ]
    const int* __restrict__ idx_in,  // [B*TP, VS]
    const float* __restrict__ w_in,  // [B*TP, VS]
    float* __restrict__ z)           // [B*TP, NQ]
{
  const int bp = blockIdx.x, b = bp >> 7;
  const int tid = threadIdx.x;
  const int wave = tid >> 6, lane = tid & 63;

  __shared__ __align__(16) float xg[VS][260];   // 1040B rows, 16B-aligned

  // lane v (<48) holds idx[v], w[v]
  int myidx = 0; float myw = 0.0f;
  if (lane < VS) {
    myidx = idx_in[(size_t)bp * VS + lane];
    myw   = w_in[(size_t)bp * VS + lane];
  }

  // gather: wave w loads rows v = 6w .. 6w+5 (full-row b128, coalesced)
#pragma unroll
  for (int i = 0; i < 6; i++) {
    int v = wave * 6 + i;
    int row = __shfl(myidx, v, 64);
    float4 f = *(const float4*)(x + ((size_t)b * TT + row) * EMB + lane * 4);
    *(float4*)&xg[v][lane * 4] = f;
  }
  __syncthreads();

  // this wave's head: q in registers
  const int h = wave;
  float4 q4 = *(const float4*)(qk + (size_t)bp * NQ + h * 256 + lane * 4);

  // dots, 4-way ILP; lane v ends holding dot[v]
  float mydot = 0.0f;
#pragma unroll
  for (int v0 = 0; v0 < VS; v0 += 4) {
    float p0, p1, p2, p3;
    {
      float4 a = *(const float4*)&xg[v0 + 0][lane * 4];
      float4 bb = *(const float4*)&xg[v0 + 1][lane * 4];
      float4 c = *(const float4*)&xg[v0 + 2][lane * 4];
      float4 d = *(const float4*)&xg[v0 + 3][lane * 4];
      p0 = q4.x * a.x + q4.y * a.y + q4.z * a.z + q4.w * a.w;
      p1 = q4.x * bb.x + q4.y * bb.y + q4.z * bb.z + q4.w * bb.w;
      p2 = q4.x * c.x + q4.y * c.y + q4.z * c.z + q4.w * c.w;
      p3 = q4.x * d.x + q4.y * d.y + q4.z * d.z + q4.w * d.w;
    }
#pragma unroll
    for (int m = 32; m >= 1; m >>= 1) {
      p0 += __shfl_xor(p0, m, 64);
      p1 += __shfl_xor(p1, m, 64);
      p2 += __shfl_xor(p2, m, 64);
      p3 += __shfl_xor(p3, m, 64);
    }
    mydot = (lane == v0 + 0) ? p0 : mydot;
    mydot = (lane == v0 + 1) ? p1 : mydot;
    mydot = (lane == v0 + 2) ? p2 : mydot;
    mydot = (lane == v0 + 3) ? p3 : mydot;
  }

  // in-wave softmax over lanes 0..47
  float logit = (lane < VS) ? myw * mydot : -1e30f;
  float mx = logit;
#pragma unroll
  for (int m = 32; m >= 1; m >>= 1) mx = fmaxf(mx, __shfl_xor(mx, m, 64));
  float e = (lane < VS) ? __expf(logit - mx) : 0.0f;
  float s = e;
#pragma unroll
  for (int m = 32; m >= 1; m >>= 1) s += __shfl_xor(s, m, 64);
  const float att = e / s;   // lane v holds att[v]

  // z: lane covers dims lane*4..+3
  float4 acc = make_float4(0.f, 0.f, 0.f, 0.f);
#pragma unroll 4
  for (int v = 0; v < VS; v++) {
    float a = __shfl(att, v, 64);
    float4 xv = *(const float4*)&xg[v][lane * 4];
    acc.x = fmaf(a, xv.x, acc.x);
    acc.y = fmaf(a, xv.y, acc.y);
    acc.z = fmaf(a, xv.z, acc.z);
    acc.w = fmaf(a, xv.w, acc.w);
  }
  *(float4*)(z + (size_t)bp * NQ + h * 256 + lane * 4) = acc;
}

// ---------------------------------------------------------------------------
// Final output pass: out[b,t,:] = bu + (t sel ? sum_h part[h][bp] : 0)
// ---------------------------------------------------------------------------
__global__ __launch_bounds__(256) void final_out(
    const float* __restrict__ part,  // [8][512][256]
    const float* __restrict__ bu,
    float* __restrict__ out)
{
  int i4 = blockIdx.x * 256 + threadIdx.x;     // float4 index
  const int e4 = i4 & 63;
  const int row = i4 >> 6;                      // b*TT + t
  const int t = row & (TT - 1), b = row >> 12;
  float4 r = ((const float4*)bu)[e4];
  if ((t & 31) == 31) {
    const int bp = b * TP + (t >> 5);
#pragma unroll
    for (int h = 0; h < HEADS; h++) {
      float4 pv = *(const float4*)&part[((size_t)h * (BB * TP) + bp) * EMB + e4 * 4];
      r.x += pv.x; r.y += pv.y; r.z += pv.z; r.w += pv.w;
    }
  }
  ((float4*)out)[i4] = r;
}

// ---------------------------------------------------------------------------
extern "C" void kernel_launch(void* const* d_in, const int* in_sizes, int n_in,
                              void* d_out, int out_size, void* d_ws, size_t ws_size,
                              hipStream_t stream) {
  const float* x  = (const float*)d_in[0];
  const float* Wq = (const float*)d_in[1];
  const float* Wk = (const float*)d_in[2];
  const float* Wv = (const float*)d_in[3];
  const float* Wu = (const float*)d_in[4];
  const float* bu = (const float*)d_in[5];
  const float* W1 = (const float*)d_in[6];
  const float* b1 = (const float*)d_in[7];
  const float* W2 = (const float*)d_in[8];
  const float* b2 = (const float*)d_in[9];
  float* out = (float*)d_out;

  // ---- workspace layout (~19 MB) ----
  char* ws = (char*)d_ws;
  size_t off = 0;
  auto alloc = [&](size_t bytes) { char* p = ws + off; off += (bytes + 255) & ~(size_t)255; return p; };
  float* xsel  = (float*)alloc((size_t)BB * TP * EMB * 4);      // 0.5 MB
  float* hid0  = (float*)alloc((size_t)BB * TP * HID * 4);      // 2 MB
  float* M8    = (float*)alloc((size_t)HEADS * EMB * EMB * 4);  // 2 MB
  float* PV    = (float*)alloc((size_t)HEADS * EMB * EMB * 4);  // 2 MB
  float* qk    = (float*)alloc((size_t)BB * TP * NQ * 4);       // 4 MB
  float* zbuf  = (float*)alloc((size_t)BB * TP * NQ * 4);       // 4 MB
  float* part  = (float*)alloc((size_t)HEADS * BB * TP * EMB * 4); // 4 MB
  int*   idxb  = (int*)  alloc((size_t)BB * TP * VS * 4);
  float* wts   = (float*)alloc((size_t)BB * TP * VS * 4);
  int*   grand = (int*)  alloc((size_t)BB * TP * KMIX * GADD * 4);
  int*   rrand = (int*)  alloc((size_t)BB * TP * KMIX * RADD * 4);

  // 1. RNG + sel-row extraction (fused)
  init_kernel<<<dim3(BB * TP + 32), dim3(256), 0, stream>>>(x, xsel, grand, rrand);

  // 2. weight precompute: M_h (NT, scaled) + PV_h (NN), one launch
  wpre_kernel<<<dim3(EMB / 64, EMB / 32, 2 * HEADS), dim3(256), 0, stream>>>(
      Wq, Wk, Wv, Wu, M8, PV);

  // 3. MLP hidden
  gemm_nn<<<dim3(HID / 64, (BB * TP) / 32, 1), dim3(256), 0, stream>>>(
      xsel, EMB, 0, W1, HID, 0, hid0, HID, 0, EMB);

  // 4. params (indices/weights)
  params2_kernel<<<dim3(BB * TP), dim3(256), 0, stream>>>(
      hid0, W1, b1, W2, b2, grand, rrand, idxb, wts);

  // 5. qk[bp, h] = xsel @ M_h
  gemm_nn<<<dim3(EMB / 64, (BB * TP) / 32, HEADS), dim3(256), 0, stream>>>(
      xsel, EMB, 0, M8, EMB, (size_t)EMB * EMB, qk, NQ, 256, EMB);

  // 6. fused attention (gather + dots + softmax + z), wave-per-head
  attn4_kernel<<<dim3(BB * TP), dim3(512), 0, stream>>>(
      x, qk, idxb, wts, zbuf);

  // 7. part_h = z_h @ PV_h
  gemm_nn<<<dim3(EMB / 64, (BB * TP) / 32, HEADS), dim3(256), 0, stream>>>(
      zbuf, NQ, 256, PV, EMB, (size_t)EMB * EMB, part, EMB, (size_t)BB * TP * EMB, EMB);

  // 8. final output (bu background + scatter-sum of head partials)
  final_out<<<dim3((BB * TT * EMB / 4) / 256), dim3(256), 0, stream>>>(
      part, bu, out);
}

// Round 9
// 74.672 us; speedup vs baseline: 1.3704x; 1.3704x over previous
//
#include <hip/hip_runtime.h>
#include <stdint.h>

// ---------------------------------------------------------------------------
// Problem constants (from reference)
// ---------------------------------------------------------------------------
#define EMB   256
#define HEADS 8
#define KMIX  8
#define GADD  2
#define RADD  2
#define REGION 64
#define STRIDE 32
#define BB    4
#define TT    4096
#define TP    128
#define VS    48
#define HID   1024
#define NQ    2048

// ---------------------------------------------------------------------------
// Threefry-2x32 (JAX exact, partitionable mode)
// ---------------------------------------------------------------------------
__device__ __forceinline__ uint32_t rotl32(uint32_t x, int d) {
  return (x << d) | (x >> (32 - d));
}
__device__ __forceinline__ void tf2x32(uint32_t k0, uint32_t k1,
                                       uint32_t x0, uint32_t x1,
                                       uint32_t& o0, uint32_t& o1) {
  uint32_t ks2 = k0 ^ k1 ^ 0x1BD11BDAu;
  x0 += k0; x1 += k1;
#define TFR(r) { x0 += x1; x1 = rotl32(x1, r); x1 ^= x0; }
  TFR(13) TFR(15) TFR(26) TFR(6)
  x0 += k1; x1 += ks2 + 1u;
  TFR(17) TFR(29) TFR(16) TFR(24)
  x0 += ks2; x1 += k0 + 2u;
  TFR(13) TFR(15) TFR(26) TFR(6)
  x0 += k0; x1 += k1 + 3u;
  TFR(17) TFR(29) TFR(16) TFR(24)
  x0 += k1; x1 += ks2 + 4u;
  TFR(13) TFR(15) TFR(26) TFR(6)
  x0 += ks2; x1 += k0 + 5u;
#undef TFR
  o0 = x0; o1 = x1;
}

// sel-row mapping: logical row m (0..511) -> x row
__device__ __forceinline__ size_t selrow(int m) {
  return (size_t)(m >> 7) * TT + ((m & 127) * STRIDE + STRIDE - 1);
}

// ---------------------------------------------------------------------------
// phase1: flat grid. bid<512: wpre (zz<8: M8 = Wq_h Wk_h^T/16 NT; else PV =
// Wv_h Wu_h NN). bid>=512: MLP hidden = xsel @ W1 (reads sel rows of x).
// ---------------------------------------------------------------------------
__global__ __launch_bounds__(256) void phase1_kernel(
    const float* __restrict__ Wq, const float* __restrict__ Wk,
    const float* __restrict__ Wv, const float* __restrict__ Wu,
    const float* __restrict__ x,  const float* __restrict__ W1,
    float* __restrict__ M8, float* __restrict__ PV, float* __restrict__ hid0)
{
  const int bid = blockIdx.x;
  const int tid = threadIdx.x;
  const int tx = tid & 15, ty = tid >> 4;

  __shared__ float As[32][33];
  __shared__ __align__(16) float Braw[64 * 33];   // NT: [64][33]; NN: [32][64]

  float acc[2][4];
#pragma unroll
  for (int i = 0; i < 2; i++)
#pragma unroll
    for (int j = 0; j < 4; j++) acc[i][j] = 0.0f;

  if (bid < 512) {
    const int zz = bid >> 5, rem = bid & 31;
    const int n0 = (rem & 3) * 64, m0 = (rem >> 2) * 32;
    if (zz < HEADS) {
      // NT: A = Wq_h (lda NQ), B = Wk_h (ldb NQ), C = M8_h, scale 1/16
      const float* A = Wq + zz * 256;
      const float* B = Wk + zz * 256;
      float* C = M8 + (size_t)zz * EMB * EMB;
      for (int k0 = 0; k0 < EMB; k0 += 32) {
        {
          int r = tid >> 3, kq = tid & 7;
          float4 v = *(const float4*)(A + (size_t)(m0 + r) * NQ + k0 + kq * 4);
          As[r][kq * 4 + 0] = v.x; As[r][kq * 4 + 1] = v.y;
          As[r][kq * 4 + 2] = v.z; As[r][kq * 4 + 3] = v.w;
        }
#pragma unroll
        for (int rr = 0; rr < 2; rr++) {
          int c = tid * 2 + rr;
          int r = c >> 3, kq = c & 7;
          float4 v = *(const float4*)(B + (size_t)(n0 + r) * NQ + k0 + kq * 4);
          Braw[r * 33 + kq * 4 + 0] = v.x; Braw[r * 33 + kq * 4 + 1] = v.y;
          Braw[r * 33 + kq * 4 + 2] = v.z; Braw[r * 33 + kq * 4 + 3] = v.w;
        }
        __syncthreads();
#pragma unroll
        for (int kk = 0; kk < 32; kk++) {
          float a0 = As[ty * 2 + 0][kk], a1 = As[ty * 2 + 1][kk];
          float b0 = Braw[(tx * 4 + 0) * 33 + kk];
          float b1 = Braw[(tx * 4 + 1) * 33 + kk];
          float b2 = Braw[(tx * 4 + 2) * 33 + kk];
          float b3 = Braw[(tx * 4 + 3) * 33 + kk];
          acc[0][0] = fmaf(a0, b0, acc[0][0]); acc[0][1] = fmaf(a0, b1, acc[0][1]);
          acc[0][2] = fmaf(a0, b2, acc[0][2]); acc[0][3] = fmaf(a0, b3, acc[0][3]);
          acc[1][0] = fmaf(a1, b0, acc[1][0]); acc[1][1] = fmaf(a1, b1, acc[1][1]);
          acc[1][2] = fmaf(a1, b2, acc[1][2]); acc[1][3] = fmaf(a1, b3, acc[1][3]);
        }
        __syncthreads();
      }
#pragma unroll
      for (int i = 0; i < 2; i++) {
        float* cp = C + (size_t)(m0 + ty * 2 + i) * EMB + n0 + tx * 4;
        *(float4*)cp = make_float4(acc[i][0] * 0.0625f, acc[i][1] * 0.0625f,
                                   acc[i][2] * 0.0625f, acc[i][3] * 0.0625f);
      }
    } else {
      // NN: A = Wv_h (lda NQ), W = Wu_h (ldw EMB), C = PV_h
      const int hh = zz - HEADS;
      const float* A = Wv + hh * 256;
      const float* W = Wu + (size_t)hh * 256 * EMB;
      float* C = PV + (size_t)hh * EMB * EMB;
      for (int k0 = 0; k0 < EMB; k0 += 32) {
        {
          int r = tid >> 3, kq = tid & 7;
          float4 v = *(const float4*)(A + (size_t)(m0 + r) * NQ + k0 + kq * 4);
          As[r][kq * 4 + 0] = v.x; As[r][kq * 4 + 1] = v.y;
          As[r][kq * 4 + 2] = v.z; As[r][kq * 4 + 3] = v.w;
        }
#pragma unroll
        for (int rr = 0; rr < 2; rr++) {
          int c = tid * 2 + rr;
          int kk = c >> 4, n4 = c & 15;
          *(float4*)(&Braw[kk * 64 + n4 * 4]) =
              *(const float4*)(W + (size_t)(k0 + kk) * EMB + n0 + n4 * 4);
        }
        __syncthreads();
#pragma unroll
        for (int kk = 0; kk < 32; kk++) {
          float a0 = As[ty * 2 + 0][kk], a1 = As[ty * 2 + 1][kk];
          float4 b4 = *(const float4*)&Braw[kk * 64 + tx * 4];
          acc[0][0] = fmaf(a0, b4.x, acc[0][0]); acc[0][1] = fmaf(a0, b4.y, acc[0][1]);
          acc[0][2] = fmaf(a0, b4.z, acc[0][2]); acc[0][3] = fmaf(a0, b4.w, acc[0][3]);
          acc[1][0] = fmaf(a1, b4.x, acc[1][0]); acc[1][1] = fmaf(a1, b4.y, acc[1][1]);
          acc[1][2] = fmaf(a1, b4.z, acc[1][2]); acc[1][3] = fmaf(a1, b4.w, acc[1][3]);
        }
        __syncthreads();
      }
#pragma unroll
      for (int i = 0; i < 2; i++) {
        float* cp = C + (size_t)(m0 + ty * 2 + i) * EMB + n0 + tx * 4;
        *(float4*)cp = make_float4(acc[i][0], acc[i][1], acc[i][2], acc[i][3]);
      }
    }
  } else {
    // MLP hidden: A = sel rows of x (k=256), W = W1 (ldw HID), C = hid0
    const int idx = bid - 512;
    const int n0 = (idx & 15) * 64, m0 = (idx >> 4) * 32;
    for (int k0 = 0; k0 < EMB; k0 += 32) {
      {
        int r = tid >> 3, kq = tid & 7;
        float4 v = *(const float4*)(x + selrow(m0 + r) * EMB + k0 + kq * 4);
        As[r][kq * 4 + 0] = v.x; As[r][kq * 4 + 1] = v.y;
        As[r][kq * 4 + 2] = v.z; As[r][kq * 4 + 3] = v.w;
      }
#pragma unroll
      for (int rr = 0; rr < 2; rr++) {
        int c = tid * 2 + rr;
        int kk = c >> 4, n4 = c & 15;
        *(float4*)(&Braw[kk * 64 + n4 * 4]) =
            *(const float4*)(W1 + (size_t)(k0 + kk) * HID + n0 + n4 * 4);
      }
      __syncthreads();
#pragma unroll
      for (int kk = 0; kk < 32; kk++) {
        float a0 = As[ty * 2 + 0][kk], a1 = As[ty * 2 + 1][kk];
        float4 b4 = *(const float4*)&Braw[kk * 64 + tx * 4];
        acc[0][0] = fmaf(a0, b4.x, acc[0][0]); acc[0][1] = fmaf(a0, b4.y, acc[0][1]);
        acc[0][2] = fmaf(a0, b4.z, acc[0][2]); acc[0][3] = fmaf(a0, b4.w, acc[0][3]);
        acc[1][0] = fmaf(a1, b4.x, acc[1][0]); acc[1][1] = fmaf(a1, b4.y, acc[1][1]);
        acc[1][2] = fmaf(a1, b4.z, acc[1][2]); acc[1][3] = fmaf(a1, b4.w, acc[1][3]);
      }
      __syncthreads();
    }
#pragma unroll
    for (int i = 0; i < 2; i++) {
      float* cp = hid0 + (size_t)(m0 + ty * 2 + i) * HID + n0 + tx * 4;
      *(float4*)cp = make_float4(acc[i][0], acc[i][1], acc[i][2], acc[i][3]);
    }
  }
}

// ---------------------------------------------------------------------------
__device__ __forceinline__ float softplus_f(float v) {
  return fmaxf(v, 0.0f) + log1pf(expf(-fabsf(v)));
}

// ---------------------------------------------------------------------------
// phase2: flat grid. bid<512: qk GEMM (qk_h = xsel @ M_h, sel rows of x).
// bid>=512: params (MLP finish + indices/weights, inline RNG).
// ---------------------------------------------------------------------------
__global__ __launch_bounds__(256) void phase2_kernel(
    const float* __restrict__ x,  const float* __restrict__ M8,
    const float* __restrict__ hid0,
    const float* __restrict__ W1, const float* __restrict__ b1,
    const float* __restrict__ W2, const float* __restrict__ b2,
    float* __restrict__ qk, int* __restrict__ idx_out, float* __restrict__ w_out)
{
  const int bid = blockIdx.x;
  const int tid = threadIdx.x;

  if (bid < 512) {
    // ---- qk GEMM ----
    const int h = bid >> 6, rem = bid & 63;
    const int n0 = (rem & 3) * 64, m0 = (rem >> 2) * 32;
    const int tx = tid & 15, ty = tid >> 4;
    const float* W = M8 + (size_t)h * EMB * EMB;

    __shared__ float As[32][33];
    __shared__ __align__(16) float Bs[32][64];

    float acc[2][4];
#pragma unroll
    for (int i = 0; i < 2; i++)
#pragma unroll
      for (int j = 0; j < 4; j++) acc[i][j] = 0.0f;

    for (int k0 = 0; k0 < EMB; k0 += 32) {
      {
        int r = tid >> 3, kq = tid & 7;
        float4 v = *(const float4*)(x + selrow(m0 + r) * EMB + k0 + kq * 4);
        As[r][kq * 4 + 0] = v.x; As[r][kq * 4 + 1] = v.y;
        As[r][kq * 4 + 2] = v.z; As[r][kq * 4 + 3] = v.w;
      }
#pragma unroll
      for (int rr = 0; rr < 2; rr++) {
        int c = tid * 2 + rr;
        int kk = c >> 4, n4 = c & 15;
        *(float4*)(&Bs[kk][n4 * 4]) =
            *(const float4*)(W + (size_t)(k0 + kk) * EMB + n0 + n4 * 4);
      }
      __syncthreads();
#pragma unroll
      for (int kk = 0; kk < 32; kk++) {
        float a0 = As[ty * 2 + 0][kk], a1 = As[ty * 2 + 1][kk];
        float4 b4 = *(const float4*)&Bs[kk][tx * 4];
        acc[0][0] = fmaf(a0, b4.x, acc[0][0]); acc[0][1] = fmaf(a0, b4.y, acc[0][1]);
        acc[0][2] = fmaf(a0, b4.z, acc[0][2]); acc[0][3] = fmaf(a0, b4.w, acc[0][3]);
        acc[1][0] = fmaf(a1, b4.x, acc[1][0]); acc[1][1] = fmaf(a1, b4.y, acc[1][1]);
        acc[1][2] = fmaf(a1, b4.z, acc[1][2]); acc[1][3] = fmaf(a1, b4.w, acc[1][3]);
      }
      __syncthreads();
    }
#pragma unroll
    for (int i = 0; i < 2; i++) {
      float* cp = qk + (size_t)(m0 + ty * 2 + i) * NQ + h * 256 + n0 + tx * 4;
      *(float4*)cp = make_float4(acc[i][0], acc[i][1], acc[i][2], acc[i][3]);
    }
  } else {
    // ---- params ----
    const int bp = bid - 512;
    const int b = bp >> 7, p = bp & 127;
    const int selp = STRIDE * p + STRIDE - 1;
    const float coordp = (float)p / (float)TP;

    __shared__ float shid[HID];
    __shared__ float spartial[256];
    __shared__ float spar[2 * KMIX];
    __shared__ float sm[KMIX], ss[KMIX];
    __shared__ int   sidx[VS];
    __shared__ float sidxf[VS];
    __shared__ int   svalid[VS];
    __shared__ float sprops[KMIX][VS];
    __shared__ float sden[KMIX];
    __shared__ int   sgrand[16], srrand[16];

    // inline RNG (16 grand + 16 rrand values for this bp)
    if (tid < 16) {
      uint32_t i = (uint32_t)(bp * 16 + tid);
      uint32_t kg0, kg1, kr0, kr1, g2k0, g2k1, r2k0, r2k1, o0, o1;
      tf2x32(0u, 42u, 0u, 0u, kg0, kg1);
      tf2x32(0u, 42u, 0u, 1u, kr0, kr1);
      tf2x32(kg0, kg1, 0u, 1u, g2k0, g2k1);
      tf2x32(kr0, kr1, 0u, 1u, r2k0, r2k1);
      tf2x32(g2k0, g2k1, 0u, i, o0, o1);
      sgrand[tid] = (int)((o0 ^ o1) & 4095u);
      tf2x32(r2k0, r2k1, 0u, i, o0, o1);
      srrand[tid] = (int)((o0 ^ o1) & 63u);
    }

#pragma unroll
    for (int q = 0; q < HID / 256; q++) {
      int j = q * 256 + tid;
      shid[j] = fmaxf(hid0[(size_t)bp * HID + j] + coordp * W1[(size_t)EMB * HID + j] + b1[j], 0.0f);
    }
    __syncthreads();

    {
      int o = tid & 15, g = tid >> 4;
      float pa = 0.0f;
      for (int jj = 0; jj < 64; jj++) {
        int j = g * 64 + jj;
        pa = fmaf(shid[j], W2[j * (2 * KMIX) + o], pa);
      }
      spartial[o * 16 + g] = pa;
    }
    __syncthreads();
    if (tid < 2 * KMIX) {
      float acc = 0.0f;
      for (int g = 0; g < 16; g++) acc += spartial[tid * 16 + g];
      spar[tid] = acc + b2[tid];
    }
    __syncthreads();

    if (tid < KMIX) {
      float m = (float)selp - 3.0f * softplus_f(spar[tid]);
      m = fminf(fmaxf(m, 0.0f), (float)(TT - 1));
      sm[tid] = m;
      ss[tid] = (softplus_f(spar[KMIX + tid] + 2.0f) + 0.05f) * (float)TT * 0.1f;
    }
    __syncthreads();

    if (tid < VS) {
      int kk = tid / 6, jj = tid % 6;
      float fl = floorf(sm[kk]);
      float v;
      if (jj == 0) v = fl;
      else if (jj == 1) v = fl + 1.0f;
      else if (jj < 4) v = (float)sgrand[kk * GADD + (jj - 2)];
      else {
        float lo = fminf(fmaxf(fl - (float)(REGION / 2), 0.0f), (float)(TT - REGION));
        v = lo + (float)srrand[kk * RADD + (jj - 4)];
      }
      v = fminf(fmaxf(v, 0.0f), (float)(TT - 1));
      int ii = (int)v;
      sidx[tid] = ii;
      sidxf[tid] = (float)ii;
    }
    __syncthreads();

    if (tid < VS) {
      int d = 0;
      for (int u = 0; u < tid; u++) d |= (sidx[u] == sidx[tid]);
      svalid[tid] = (!d) && (sidx[tid] <= selp);
    }
    __syncthreads();

    for (int l = tid; l < KMIX * VS; l += 256) {
      int kk = l / VS, v = l - kk * VS;
      float zz = (sidxf[v] - sm[kk]) / ss[kk];
      sprops[kk][v] = svalid[v] ? expf(-0.5f * zz * zz) : 0.0f;
    }
    __syncthreads();
    if (tid < KMIX) {
      float den = 0.0f;
      for (int v = 0; v < VS; v++) den += sprops[tid][v];
      sden[tid] = den;
    }
    __syncthreads();

    if (tid < VS) {
      float w = 0.0f;
      for (int kk = 0; kk < KMIX; kk++) w += sprops[kk][tid] / sden[kk];
      w_out[(size_t)bp * VS + tid] = w;
      idx_out[(size_t)bp * VS + tid] = sidx[tid];
    }
  }
}

// ---------------------------------------------------------------------------
// attn5: one 256-thread block per bp; 4 waves x 2 heads each.
// dots: lane = (vsub, dgrp) covers 16 dims of one v; 2 shuffle levels + LDS
// partials (conflict-free). z: b128 broadcast of att + shared xg reads.
// ---------------------------------------------------------------------------
__global__ __launch_bounds__(256) void attn5_kernel(
    const float* __restrict__ x,     // [B,T,EMB]
    const float* __restrict__ qk,    // [B*TP, NQ]
    const int* __restrict__ idx_in,  // [B*TP, VS]
    const float* __restrict__ w_in,  // [B*TP, VS]
    float* __restrict__ z)           // [B*TP, NQ]
{
  const int bp = blockIdx.x, b = bp >> 7;
  const int tid = threadIdx.x;
  const int wave = tid >> 6, lane = tid & 63;
  const int vsub = lane >> 4, dgrp = lane & 15;
  const int h0 = wave * 2, h1 = h0 + 1;

  __shared__ __align__(16) float xg[VS][260];     // 49920 B
  __shared__ float part[HEADS][VS][5];            // 7680 B (stride 5: <=2-way)
  __shared__ __align__(16) float sa[HEADS][VS];   // 1536 B

  int myidx = 0; float myw = 0.0f;
  if (lane < VS) {
    myidx = idx_in[(size_t)bp * VS + lane];
    myw   = w_in[(size_t)bp * VS + lane];
  }

  // gather: wave loads rows v = wave*12 .. +11 (full-row b128, coalesced)
#pragma unroll
  for (int i = 0; i < 12; i++) {
    int v = wave * 12 + i;
    int row = __shfl(myidx, v, 64);
    float4 f = *(const float4*)(x + ((size_t)b * TT + row) * EMB + lane * 4);
    *(float4*)&xg[v][lane * 4] = f;
  }

  // q registers: both heads, dims dgrp*16 .. +15
  float4 q0[4], q1[4];
#pragma unroll
  for (int j = 0; j < 4; j++) {
    q0[j] = *(const float4*)(qk + (size_t)bp * NQ + h0 * 256 + dgrp * 16 + j * 4);
    q1[j] = *(const float4*)(qk + (size_t)bp * NQ + h1 * 256 + dgrp * 16 + j * 4);
  }
  __syncthreads();

  // dots: per iter 4 v's; 16 dims/lane; 2 shuffle levels; LDS partials
#pragma unroll
  for (int it = 0; it < 12; it++) {
    int v = it * 4 + vsub;
    float p0 = 0.0f, p1 = 0.0f;
#pragma unroll
    for (int j = 0; j < 4; j++) {
      float4 xv = *(const float4*)&xg[v][dgrp * 16 + j * 4];
      p0 = fmaf(q0[j].x, xv.x, fmaf(q0[j].y, xv.y, fmaf(q0[j].z, xv.z, fmaf(q0[j].w, xv.w, p0))));
      p1 = fmaf(q1[j].x, xv.x, fmaf(q1[j].y, xv.y, fmaf(q1[j].z, xv.z, fmaf(q1[j].w, xv.w, p1))));
    }
    p0 += __shfl_xor(p0, 1, 64); p0 += __shfl_xor(p0, 2, 64);
    p1 += __shfl_xor(p1, 1, 64); p1 += __shfl_xor(p1, 2, 64);
    if ((dgrp & 3) == 0) {
      part[h0][v][dgrp >> 2] = p0;
      part[h1][v][dgrp >> 2] = p1;
    }
  }
  __syncthreads();

  // finalize dots + in-wave softmax, both heads; att -> sa
#pragma unroll
  for (int hh = 0; hh < 2; hh++) {
    const int h = h0 + hh;
    float logit = -1e30f;
    if (lane < VS) {
      float dot = part[h][lane][0] + part[h][lane][1] + part[h][lane][2] + part[h][lane][3];
      logit = myw * dot;
    }
    float mx = logit;
#pragma unroll
    for (int m = 32; m >= 1; m >>= 1) mx = fmaxf(mx, __shfl_xor(mx, m, 64));
    float e = (lane < VS) ? __expf(logit - mx) : 0.0f;
    float s = e;
#pragma unroll
    for (int m = 32; m >= 1; m >>= 1) s += __shfl_xor(s, m, 64);
    if (lane < VS) sa[h][lane] = e / s;
  }
  __syncthreads();

  // z: lane covers dims lane*4; att via b128 broadcast; xg read shared by both heads
  float4 a0 = make_float4(0.f, 0.f, 0.f, 0.f);
  float4 a1 = make_float4(0.f, 0.f, 0.f, 0.f);
#pragma unroll
  for (int v0 = 0; v0 < VS; v0 += 4) {
    float4 at0 = *(const float4*)&sa[h0][v0];
    float4 at1 = *(const float4*)&sa[h1][v0];
#pragma unroll
    for (int k = 0; k < 4; k++) {
      float4 xv = *(const float4*)&xg[v0 + k][lane * 4];
      float c0 = (k == 0) ? at0.x : (k == 1) ? at0.y : (k == 2) ? at0.z : at0.w;
      float c1 = (k == 0) ? at1.x : (k == 1) ? at1.y : (k == 2) ? at1.z : at1.w;
      a0.x = fmaf(c0, xv.x, a0.x); a0.y = fmaf(c0, xv.y, a0.y);
      a0.z = fmaf(c0, xv.z, a0.z); a0.w = fmaf(c0, xv.w, a0.w);
      a1.x = fmaf(c1, xv.x, a1.x); a1.y = fmaf(c1, xv.y, a1.y);
      a1.z = fmaf(c1, xv.z, a1.z); a1.w = fmaf(c1, xv.w, a1.w);
    }
  }
  *(float4*)(z + (size_t)bp * NQ + h0 * 256 + lane * 4) = a0;
  *(float4*)(z + (size_t)bp * NQ + h1 * 256 + lane * 4) = a1;
}

// ---------------------------------------------------------------------------
// partPV: part_h = z_h @ PV_h (batched over heads). Tile 32x64, BK=32.
// ---------------------------------------------------------------------------
__global__ __launch_bounds__(256) void gemm_nn(
    const float* __restrict__ A, int lda, size_t Az,
    const float* __restrict__ W, int ldw, size_t Wz,
    float* __restrict__ C, int ldc, size_t Cz,
    int kLen)
{
  A += (size_t)blockIdx.z * Az;
  W += (size_t)blockIdx.z * Wz;
  C += (size_t)blockIdx.z * Cz;
  const int tid = threadIdx.x;
  const int tx = tid & 15, ty = tid >> 4;
  const int n0 = blockIdx.x * 64, m0 = blockIdx.y * 32;

  __shared__ float As[32][33];
  __shared__ __align__(16) float Bs[32][64];

  float acc[2][4];
#pragma unroll
  for (int i = 0; i < 2; i++)
#pragma unroll
    for (int j = 0; j < 4; j++) acc[i][j] = 0.0f;

  for (int k0 = 0; k0 < kLen; k0 += 32) {
    {
      int r = tid >> 3, kq = tid & 7;
      float4 v = *(const float4*)(A + (size_t)(m0 + r) * lda + k0 + kq * 4);
      As[r][kq * 4 + 0] = v.x; As[r][kq * 4 + 1] = v.y;
      As[r][kq * 4 + 2] = v.z; As[r][kq * 4 + 3] = v.w;
    }
#pragma unroll
    for (int rr = 0; rr < 2; rr++) {
      int c = tid * 2 + rr;
      int kk = c >> 4, n4 = c & 15;
      *(float4*)(&Bs[kk][n4 * 4]) =
          *(const float4*)(W + (size_t)(k0 + kk) * ldw + n0 + n4 * 4);
    }
    __syncthreads();
#pragma unroll
    for (int kk = 0; kk < 32; kk++) {
      float a0 = As[ty * 2 + 0][kk];
      float a1 = As[ty * 2 + 1][kk];
      float4 b4 = *(const float4*)&Bs[kk][tx * 4];
      acc[0][0] = fmaf(a0, b4.x, acc[0][0]);
      acc[0][1] = fmaf(a0, b4.y, acc[0][1]);
      acc[0][2] = fmaf(a0, b4.z, acc[0][2]);
      acc[0][3] = fmaf(a0, b4.w, acc[0][3]);
      acc[1][0] = fmaf(a1, b4.x, acc[1][0]);
      acc[1][1] = fmaf(a1, b4.y, acc[1][1]);
      acc[1][2] = fmaf(a1, b4.z, acc[1][2]);
      acc[1][3] = fmaf(a1, b4.w, acc[1][3]);
    }
    __syncthreads();
  }

#pragma unroll
  for (int i = 0; i < 2; i++) {
    float* cp = C + (size_t)(m0 + ty * 2 + i) * ldc + n0 + tx * 4;
    *(float4*)cp = make_float4(acc[i][0], acc[i][1], acc[i][2], acc[i][3]);
  }
}

// ---------------------------------------------------------------------------
// Final output: out[b,t,:] = bu + (t sel ? sum_h part[h][bp] : 0)
// ---------------------------------------------------------------------------
__global__ __launch_bounds__(256) void final_out(
    const float* __restrict__ part,  // [8][512][256]
    const float* __restrict__ bu,
    float* __restrict__ out)
{
  int i4 = blockIdx.x * 256 + threadIdx.x;
  const int e4 = i4 & 63;
  const int row = i4 >> 6;
  const int t = row & (TT - 1), b = row >> 12;
  float4 r = ((const float4*)bu)[e4];
  if ((t & 31) == 31) {
    const int bp = b * TP + (t >> 5);
#pragma unroll
    for (int h = 0; h < HEADS; h++) {
      float4 pv = *(const float4*)&part[((size_t)h * (BB * TP) + bp) * EMB + e4 * 4];
      r.x += pv.x; r.y += pv.y; r.z += pv.z; r.w += pv.w;
    }
  }
  ((float4*)out)[i4] = r;
}

// ---------------------------------------------------------------------------
extern "C" void kernel_launch(void* const* d_in, const int* in_sizes, int n_in,
                              void* d_out, int out_size, void* d_ws, size_t ws_size,
                              hipStream_t stream) {
  const float* x  = (const float*)d_in[0];
  const float* Wq = (const float*)d_in[1];
  const float* Wk = (const float*)d_in[2];
  const float* Wv = (const float*)d_in[3];
  const float* Wu = (const float*)d_in[4];
  const float* bu = (const float*)d_in[5];
  const float* W1 = (const float*)d_in[6];
  const float* b1 = (const float*)d_in[7];
  const float* W2 = (const float*)d_in[8];
  const float* b2 = (const float*)d_in[9];
  float* out = (float*)d_out;

  // ---- workspace layout (~18 MB) ----
  char* ws = (char*)d_ws;
  size_t off = 0;
  auto alloc = [&](size_t bytes) { char* p = ws + off; off += (bytes + 255) & ~(size_t)255; return p; };
  float* hid0  = (float*)alloc((size_t)BB * TP * HID * 4);         // 2 MB
  float* M8    = (float*)alloc((size_t)HEADS * EMB * EMB * 4);     // 2 MB
  float* PV    = (float*)alloc((size_t)HEADS * EMB * EMB * 4);     // 2 MB
  float* qk    = (float*)alloc((size_t)BB * TP * NQ * 4);          // 4 MB
  float* zbuf  = (float*)alloc((size_t)BB * TP * NQ * 4);          // 4 MB
  float* part  = (float*)alloc((size_t)HEADS * BB * TP * EMB * 4); // 4 MB
  int*   idxb  = (int*)  alloc((size_t)BB * TP * VS * 4);
  float* wts   = (float*)alloc((size_t)BB * TP * VS * 4);

  // L1: weight precompute (M8, PV) + MLP hidden
  phase1_kernel<<<dim3(768), dim3(256), 0, stream>>>(
      Wq, Wk, Wv, Wu, x, W1, M8, PV, hid0);

  // L2: params (inline RNG) + qk GEMM
  phase2_kernel<<<dim3(1024), dim3(256), 0, stream>>>(
      x, M8, hid0, W1, b1, W2, b2, qk, idxb, wts);

  // L3: fused attention
  attn5_kernel<<<dim3(BB * TP), dim3(256), 0, stream>>>(
      x, qk, idxb, wts, zbuf);

  // L4: part_h = z_h @ PV_h
  gemm_nn<<<dim3(EMB / 64, (BB * TP) / 32, HEADS), dim3(256), 0, stream>>>(
      zbuf, NQ, 256, PV, EMB, (size_t)EMB * EMB, part, EMB, (size_t)BB * TP * EMB, EMB);

  // L5: final output
  final_out<<<dim3((BB * TT * EMB / 4) / 256), dim3(256), 0, stream>>>(
      part, bu, out);
}